// Round 5
// baseline (13613.722 us; speedup 1.0000x reference)
//
#include <hip/hip_runtime.h>
#include <stdint.h>

#define T_SEQ 2048
#define D_MODEL 2048
#define N_HEAD 16
#define N_KV 4
#define HD 128

// ---------------------------------------------------------------------------
// Diagnostic stamp: fill out with a code so absmax reports it.
// ---------------------------------------------------------------------------
__global__ void fill_diag(float* __restrict__ out, float val, int n) {
  int i = blockIdx.x * blockDim.x + threadIdx.x;
  if (i < n) out[i] = val;
}

// ---------------------------------------------------------------------------
// Naive tiled GEMM: C[M][N] = A[M][K] * B[N][K]^T. All fp32.
// Block (32,32), one output element per thread, 32-wide K tiles in LDS.
// ---------------------------------------------------------------------------
__global__ __launch_bounds__(1024) void gemm_naive_f32(
    const float* __restrict__ A, const float* __restrict__ B,
    float* __restrict__ C, int M, int N, int K) {
  __shared__ float As[32][33];
  __shared__ float Bs[32][33];
  const int tx = threadIdx.x, ty = threadIdx.y;
  const int row = blockIdx.x * 32 + ty;
  const int col = blockIdx.y * 32 + tx;
  float acc = 0.f;
  for (int k0 = 0; k0 < K; k0 += 32) {
    As[ty][tx] = A[(size_t)row * K + k0 + tx];
    Bs[ty][tx] = B[(size_t)(blockIdx.y * 32 + ty) * K + k0 + tx];
    __syncthreads();
#pragma unroll
    for (int kk = 0; kk < 32; kk++) acc += As[ty][kk] * Bs[tx][kk];
    __syncthreads();
  }
  C[(size_t)row * N + col] = acc;
}

// ---------------------------------------------------------------------------
// RoPE in-place (fp32): q [B*T][2048] (16 heads), K-half of kv [B*T][1024].
// out[i] = x[i]*cos - x[i+64]*sin ; out[i+64] = x[i+64]*cos + x[i]*sin
// angle = t * 10000^(-i/64)   (freq tiled twice => same angle for i and i+64)
// ---------------------------------------------------------------------------
__global__ void rope_kernel(float* __restrict__ q, float* __restrict__ kv) {
  const int row = blockIdx.x;          // b*T + t
  const int t = row & (T_SEQ - 1);
  const int tid = threadIdx.x;
  const float L2_10K_64 = 13.287712379549449f / 64.f;  // log2(10000)/64

#pragma unroll
  for (int it = 0; it < 4; it++) {     // 16 heads * 64 pairs = 1024 work items
    int idx = it * 256 + tid;
    int h = idx >> 6, i = idx & 63;
    size_t base = (size_t)row * D_MODEL + h * HD;
    float ang = (float)t * exp2f(-(float)i * L2_10K_64);
    float s, c; sincosf(ang, &s, &c);
    float x1 = q[base + i];
    float x2 = q[base + i + 64];
    q[base + i]      = x1 * c - x2 * s;
    q[base + i + 64] = x2 * c + x1 * s;
  }
  {                                    // 4 kv heads * 64 pairs = 256 work items
    int h = tid >> 6, i = tid & 63;
    size_t base = (size_t)row * (2 * N_KV * HD) + h * HD;
    float ang = (float)t * exp2f(-(float)i * L2_10K_64);
    float s, c; sincosf(ang, &s, &c);
    float x1 = kv[base + i];
    float x2 = kv[base + i + 64];
    kv[base + i]      = x1 * c - x2 * s;
    kv[base + i + 64] = x2 * c + x1 * s;
  }
}

// ---------------------------------------------------------------------------
// Naive causal attention (fp32): one block per (t, b, h). Two-pass softmax.
// ---------------------------------------------------------------------------
__global__ __launch_bounds__(256) void attn_naive(
    const float* __restrict__ q, const float* __restrict__ kv,
    float* __restrict__ y) {
  __shared__ float qs[HD];
  __shared__ float ps[T_SEQ];
  __shared__ float red[4];

  const int t  = blockIdx.x;
  const int bh = blockIdx.y;
  const int b  = bh >> 4;
  const int h  = bh & 15;
  const int hk = h >> 2;               // repeat_interleave: q-head h -> kv-head h/4
  const int tid = threadIdx.x;
  const int lane = tid & 63, wid = tid >> 6;

  const float* qrow = q + (size_t)(b * T_SEQ + t) * D_MODEL + h * HD;
  if (tid < HD) qs[tid] = qrow[tid];
  __syncthreads();

  const float* Kbase = kv + (size_t)b * T_SEQ * (2 * N_KV * HD) + hk * HD;
  const float* Vbase = Kbase + N_KV * HD;  // +512: V half of the kv row
  const float scale = 0.08838834764831845f;  // 1/sqrt(128)

  // ---- scores ----
  float lmax = -INFINITY;
  for (int tp = tid; tp <= t; tp += 256) {
    const float* krow = Kbase + (size_t)tp * (2 * N_KV * HD);
    float s = 0.f;
#pragma unroll
    for (int d = 0; d < HD; d++) s += qs[d] * krow[d];
    s *= scale;
    ps[tp] = s;
    lmax = fmaxf(lmax, s);
  }
  // ---- block max ----
#pragma unroll
  for (int off = 32; off > 0; off >>= 1) lmax = fmaxf(lmax, __shfl_xor(lmax, off, 64));
  if (lane == 0) red[wid] = lmax;
  __syncthreads();
  const float m = fmaxf(fmaxf(red[0], red[1]), fmaxf(red[2], red[3]));
  __syncthreads();  // everyone read red before reuse

  // ---- exp + block sum ----
  float lsum = 0.f;
  for (int tp = tid; tp <= t; tp += 256) {
    float w = __expf(ps[tp] - m);
    ps[tp] = w;
    lsum += w;
  }
#pragma unroll
  for (int off = 32; off > 0; off >>= 1) lsum += __shfl_xor(lsum, off, 64);
  if (lane == 0) red[wid] = lsum;
  __syncthreads();
  const float inv = 1.f / (red[0] + red[1] + red[2] + red[3]);

  // ---- PV: 2 key-strides x 128 dims ----
  const int d = tid & 127, half = tid >> 7;
  float acc = 0.f;
  for (int tp = half; tp <= t; tp += 2)
    acc += ps[tp] * Vbase[(size_t)tp * (2 * N_KV * HD) + d];
  __syncthreads();               // qs reads done; safe to reuse as scratch
  if (half == 1) qs[d] = acc;
  __syncthreads();
  if (half == 0) {
    float o = (acc + qs[d]) * inv;
    y[(size_t)(b * T_SEQ + t) * D_MODEL + h * HD + d] = o;
  }
}

// ---------------------------------------------------------------------------
extern "C" void kernel_launch(void* const* d_in, const int* in_sizes, int n_in,
                              void* d_out, int out_size, void* d_ws, size_t ws_size,
                              hipStream_t stream) {
  const float* x     = (const float*)d_in[0];  // [2,2048,2048] fp32
  const float* Wq    = (const float*)d_in[1];  // [2048,2048]
  const float* Wkv   = (const float*)d_in[2];  // [1024,2048]
  const float* Wproj = (const float*)d_in[3];  // [2048,2048]
  float* out = (float*)d_out;                  // [2,2048,2048] fp32 (reference output dtype)

  const size_t NX  = (size_t)4096 * 2048;   // 8388608
  const size_t NWQ = (size_t)2048 * 2048;   // 4194304
  const size_t NWK = (size_t)1024 * 2048;   // 2097152
  const size_t NKV = (size_t)4096 * 1024;   // 4194304
  const size_t needed_ws = (NKV + NX) * sizeof(float);  // kv + y = 50.3 MB

  // Host-side binding sanity check; on mismatch, stamp a decodable code.
  int b0 = (n_in >= 1 && (size_t)in_sizes[0] == NX);
  int b1 = (n_in >= 2 && (size_t)in_sizes[1] == NWQ);
  int b2 = (n_in >= 3 && (size_t)in_sizes[2] == NWK);
  int b3 = (n_in >= 4 && (size_t)in_sizes[3] == NWQ);
  int ws_ok = (ws_size >= needed_ws);
  int out_ok = ((size_t)out_size == NX);
  if (!(n_in == 4 && b0 && b1 && b2 && b3 && ws_ok && out_ok)) {
    float code = 1.0e6f * (float)(n_in < 10 ? n_in : 9)
               + 1.0e5f * b0 + 1.0e4f * b1 + 1.0e3f * b2 + 1.0e2f * b3
               + 10.0f * ws_ok + 40.0f * out_ok;
    int n = out_size;
    fill_diag<<<dim3((n + 255) / 256), dim3(256), 0, stream>>>(out, code, n);
    return;
  }

  // ws layout: kv (fp32, 16.8MB) | y (fp32, 33.5MB).  q lives in d_out
  // (dead before the final GEMM overwrites out; final GEMM reads only y,Wproj).
  float* kvbuf = (float*)d_ws;
  float* ybuf  = kvbuf + NKV;
  float* qbuf  = out;

  dim3 gblk(32, 32);
  gemm_naive_f32<<<dim3(128, 64), gblk, 0, stream>>>(x, Wq,  qbuf,  4096, 2048, 2048);
  gemm_naive_f32<<<dim3(128, 32), gblk, 0, stream>>>(x, Wkv, kvbuf, 4096, 1024, 2048);
  rope_kernel<<<dim3(4096), dim3(256), 0, stream>>>(qbuf, kvbuf);
  attn_naive<<<dim3(2048, 32), dim3(256), 0, stream>>>(qbuf, kvbuf, ybuf);
  gemm_naive_f32<<<dim3(128, 64), gblk, 0, stream>>>(ybuf, Wproj, out, 4096, 2048, 2048);
}

// Round 6
// 468.805 us; speedup vs baseline: 29.0392x; 29.0392x over previous
//
#include <hip/hip_runtime.h>
#include <stdint.h>

#define T_SEQ 2048
#define D_MODEL 2048
#define N_HEAD 16
#define N_KV 4
#define HD 128

typedef unsigned short us;
typedef __attribute__((ext_vector_type(8))) short bf16x8;   // 8 bf16 = 4 VGPR
typedef __attribute__((ext_vector_type(4))) float f32x4;
typedef __attribute__((ext_vector_type(8))) unsigned short u16x8;

__device__ __forceinline__ us f2bf(float f) {
  union { float f; unsigned int u; } v; v.f = f;
  unsigned int r = v.u + 0x7FFFu + ((v.u >> 16) & 1u);
  return (us)(r >> 16);
}
__device__ __forceinline__ float bf2f(us h) {
  union { unsigned int u; float f; } v; v.u = ((unsigned int)h) << 16;
  return v.f;
}

__device__ __forceinline__ void load_lds16(const void* g, void* l) {
  __builtin_amdgcn_global_load_lds(
      (const __attribute__((address_space(1))) void*)g,
      (__attribute__((address_space(3))) void*)l, 16, 0, 0);
}

__global__ void fill_diag(float* __restrict__ out, float val, int n) {
  int i = blockIdx.x * blockDim.x + threadIdx.x;
  if (i < n) out[i] = val;
}

// ---------------------------------------------------------------------------
// fp32 -> bf16 (RNE) cast, 8 elements/thread, memory-bound.
// ---------------------------------------------------------------------------
__global__ void cast_f32_bf16(const float* __restrict__ src,
                              us* __restrict__ dst, int n8) {
  int i = blockIdx.x * blockDim.x + threadIdx.x;
  if (i >= n8) return;
  const float4* s = (const float4*)src + (size_t)i * 2;
  float4 a = s[0], b = s[1];
  u16x8 o;
  o[0] = f2bf(a.x); o[1] = f2bf(a.y); o[2] = f2bf(a.z); o[3] = f2bf(a.w);
  o[4] = f2bf(b.x); o[5] = f2bf(b.y); o[6] = f2bf(b.z); o[7] = f2bf(b.w);
  *((u16x8*)dst + i) = o;
}

// ---------------------------------------------------------------------------
// C[M][N] = A[M][K] * B[N][K]^T, A,B row-major bf16, C bf16 or fp32.
// m97 structure: 128x128 tile, BK=32, global_load_lds width=16, 4 waves 64x64.
// ---------------------------------------------------------------------------
template <typename OUT>
__global__ __launch_bounds__(256) void gemm_bt(
    const us* __restrict__ A, const us* __restrict__ B,
    OUT* __restrict__ C, int M, int N, int K) {
  __shared__ us As[128 * 32];
  __shared__ us Bs[128 * 32];

  const int tid  = threadIdx.x;
  const int lane = tid & 63;
  const int wave = tid >> 6;
  const int l15  = lane & 15;
  const int quad = lane >> 4;
  const int bm = blockIdx.x * 128;
  const int bn = blockIdx.y * 128;
  const int wm = (wave & 1) * 64;
  const int wn = (wave >> 1) * 64;

  f32x4 acc[4][4];
#pragma unroll
  for (int i = 0; i < 4; i++)
#pragma unroll
    for (int j = 0; j < 4; j++) acc[i][j] = (f32x4)0.f;

  const int srow = tid >> 2;        // 0..63
  const int scol = (tid & 3) * 8;   // 0,8,16,24
  const us* Ag = A + (size_t)(bm + srow) * K + scol;
  const us* Bg = B + (size_t)(bn + srow) * K + scol;
  us* AsW = &As[tid * 8];
  us* BsW = &Bs[tid * 8];
  const size_t rowskip = (size_t)64 * K;

  for (int k0 = 0; k0 < K; k0 += 32) {
    load_lds16(Ag, AsW);
    load_lds16(Ag + rowskip, AsW + 2048);
    load_lds16(Bg, BsW);
    load_lds16(Bg + rowskip, BsW + 2048);
    Ag += 32; Bg += 32;
    __syncthreads();

    bf16x8 a[4], b[4];
#pragma unroll
    for (int mt = 0; mt < 4; mt++)
      a[mt] = *(const bf16x8*)&As[(wm + mt * 16 + l15) * 32 + quad * 8];
#pragma unroll
    for (int nt = 0; nt < 4; nt++)
      b[nt] = *(const bf16x8*)&Bs[(wn + nt * 16 + l15) * 32 + quad * 8];
#pragma unroll
    for (int mt = 0; mt < 4; mt++)
#pragma unroll
      for (int nt = 0; nt < 4; nt++)
        acc[mt][nt] = __builtin_amdgcn_mfma_f32_16x16x32_bf16(a[mt], b[nt], acc[mt][nt], 0, 0, 0);
    __syncthreads();
  }

  // C/D layout: col = lane&15, row = quad*4 + reg
#pragma unroll
  for (int mt = 0; mt < 4; mt++) {
    int row = bm + wm + mt * 16 + quad * 4;
#pragma unroll
    for (int nt = 0; nt < 4; nt++) {
      int col = bn + wn + nt * 16 + l15;
#pragma unroll
      for (int r = 0; r < 4; r++) {
        if constexpr (sizeof(OUT) == 4)
          C[(size_t)(row + r) * N + col] = acc[mt][nt][r];
        else
          C[(size_t)(row + r) * N + col] = f2bf(acc[mt][nt][r]);
      }
    }
  }
}

// ---------------------------------------------------------------------------
// RoPE in-place (bf16): q [B*T][2048] (16 heads), K-half of kv [B*T][1024].
// angle = t * 10000^(-i/64); pairs (i, i+64)
// ---------------------------------------------------------------------------
__global__ void rope_kernel(us* __restrict__ q, us* __restrict__ kv) {
  const int row = blockIdx.x;          // b*T + t
  const int t = row & (T_SEQ - 1);
  const int tid = threadIdx.x;
  const float L2_10K_64 = 13.287712379549449f / 64.f;

#pragma unroll
  for (int it = 0; it < 4; it++) {
    int idx = it * 256 + tid;
    int h = idx >> 6, i = idx & 63;
    size_t base = (size_t)row * D_MODEL + h * HD;
    float ang = (float)t * exp2f(-(float)i * L2_10K_64);
    float s, c; sincosf(ang, &s, &c);
    float x1 = bf2f(q[base + i]);
    float x2 = bf2f(q[base + i + 64]);
    q[base + i]      = f2bf(x1 * c - x2 * s);
    q[base + i + 64] = f2bf(x2 * c + x1 * s);
  }
  {
    int h = tid >> 6, i = tid & 63;
    size_t base = (size_t)row * (2 * N_KV * HD) + h * HD;
    float ang = (float)t * exp2f(-(float)i * L2_10K_64);
    float s, c; sincosf(ang, &s, &c);
    float x1 = bf2f(kv[base + i]);
    float x2 = bf2f(kv[base + i + 64]);
    kv[base + i]      = f2bf(x1 * c - x2 * s);
    kv[base + i + 64] = f2bf(x2 * c + x1 * s);
  }
}

// ---------------------------------------------------------------------------
// Causal flash attention, GQA. Block = 64 Q rows of one (b,h); 4 waves x 16.
// ---------------------------------------------------------------------------
__device__ __forceinline__ int vperm(int d) { return ((d >> 3) ^ d) & 7; }

__global__ __launch_bounds__(256) void attn_kernel(
    const us* __restrict__ q, const us* __restrict__ kv, us* __restrict__ y) {
  __shared__ us Ks[4][64][32];  // [k-slice][key][k%32]
  __shared__ us Vt[128][64];    // V^T, XOR-swizzled 8-key blocks
  __shared__ us Pl[4][16][80];  // per-wave P, padded rows

  const int tid  = threadIdx.x;
  const int lane = tid & 63;
  const int wave = tid >> 6;
  const int l15  = lane & 15;
  const int quad = lane >> 4;
  const int m0 = blockIdx.x * 64;
  const int bh = blockIdx.y;
  const int b  = bh >> 4;
  const int h  = bh & 15;
  const int hk = h >> 2;               // q-head h -> kv-head h/4

  bf16x8 qf[4];
  {
    int t_q = m0 + wave * 16 + l15;
    const us* Qrow = q + (size_t)(b * T_SEQ + t_q) * D_MODEL + h * HD;
#pragma unroll
    for (int s = 0; s < 4; s++)
      qf[s] = *(const bf16x8*)&Qrow[s * 32 + quad * 8];
  }

  f32x4 O[8];
#pragma unroll
  for (int i = 0; i < 8; i++) O[i] = (f32x4)0.f;
  float mrun[4], lrun[4];
#pragma unroll
  for (int r = 0; r < 4; r++) { mrun[r] = -INFINITY; lrun[r] = 0.f; }

  const float scale = 0.08838834764831845f;  // 1/sqrt(128)
  const us* Kg = kv + (size_t)b * T_SEQ * (2 * N_KV * HD) + hk * HD;
  const us* Vg = Kg + N_KV * HD;

  const int skey0 = tid >> 4;          // 0..15
  const int skk   = (tid & 15) * 8;    // 0..120
  const int jmax  = m0 >> 6;

  for (int j = 0; j <= jmax; j++) {
    const int k0 = j * 64;
#pragma unroll
    for (int r = 0; r < 4; r++) {
      int key = skey0 + r * 16;
      size_t roff = (size_t)(k0 + key) * (2 * N_KV * HD);
      uint4 k4 = *(const uint4*)(Kg + roff + skk);
      *(uint4*)&Ks[skk >> 5][key][skk & 31] = k4;
      u16x8 v8 = *(const u16x8*)(Vg + roff + skk);
#pragma unroll
      for (int i = 0; i < 8; i++) {
        int d = skk + i;
        Vt[d][key ^ (vperm(d) << 3)] = v8[i];
      }
    }
    __syncthreads();

    // S = Q K^T
    f32x4 S[4];
#pragma unroll
    for (int nt = 0; nt < 4; nt++) {
      f32x4 sa = (f32x4)0.f;
#pragma unroll
      for (int ks = 0; ks < 4; ks++) {
        bf16x8 kf = *(const bf16x8*)&Ks[ks][nt * 16 + l15][quad * 8];
        sa = __builtin_amdgcn_mfma_f32_16x16x32_bf16(qf[ks], kf, sa, 0, 0, 0);
      }
      S[nt] = sa;
    }

    // scale + causal mask
    const int row0 = m0 + wave * 16 + quad * 4;
#pragma unroll
    for (int nt = 0; nt < 4; nt++) {
      int col = k0 + nt * 16 + l15;
#pragma unroll
      for (int r = 0; r < 4; r++) {
        float v = S[nt][r] * scale;
        if (col > row0 + r) v = -INFINITY;
        S[nt][r] = v;
      }
    }

    // online softmax (rows live in 16-lane groups)
    float p[4][4];
#pragma unroll
    for (int r = 0; r < 4; r++) {
      float mx = fmaxf(fmaxf(S[0][r], S[1][r]), fmaxf(S[2][r], S[3][r]));
#pragma unroll
      for (int off = 1; off < 16; off <<= 1)
        mx = fmaxf(mx, __shfl_xor(mx, off, 64));
      float mnew = fmaxf(mrun[r], mx);
      float alpha = __expf(mrun[r] - mnew);
      mrun[r] = mnew;
      float sum = 0.f;
#pragma unroll
      for (int nt = 0; nt < 4; nt++) {
        float pv = __expf(S[nt][r] - mnew);
        p[nt][r] = pv;
        sum += pv;
      }
#pragma unroll
      for (int off = 1; off < 16; off <<= 1)
        sum += __shfl_xor(sum, off, 64);
      lrun[r] = lrun[r] * alpha + sum;
#pragma unroll
      for (int ot = 0; ot < 8; ot++) O[ot][r] *= alpha;
    }

    // P: C-layout -> LDS -> A-layout
#pragma unroll
    for (int nt = 0; nt < 4; nt++)
#pragma unroll
      for (int r = 0; r < 4; r++)
        Pl[wave][quad * 4 + r][nt * 16 + l15] = f2bf(p[nt][r]);
    __syncthreads();

    // O += P V
#pragma unroll
    for (int ks = 0; ks < 2; ks++) {
      bf16x8 pf = *(const bf16x8*)&Pl[wave][l15][ks * 32 + quad * 8];
#pragma unroll
      for (int ot = 0; ot < 8; ot++) {
        int dcol = ot * 16 + l15;
        bf16x8 vf = *(const bf16x8*)&Vt[dcol][(ks * 32 + quad * 8) ^ (vperm(dcol) << 3)];
        O[ot] = __builtin_amdgcn_mfma_f32_16x16x32_bf16(pf, vf, O[ot], 0, 0, 0);
      }
    }
    __syncthreads();
  }

  const int t_out = m0 + wave * 16 + quad * 4;
#pragma unroll
  for (int r = 0; r < 4; r++) {
    float inv_l = 1.f / lrun[r];
    us* yrow = y + (size_t)(b * T_SEQ + t_out + r) * D_MODEL + h * HD;
#pragma unroll
    for (int ot = 0; ot < 8; ot++)
      yrow[ot * 16 + l15] = f2bf(O[ot][r] * inv_l);
  }
}

// ---------------------------------------------------------------------------
extern "C" void kernel_launch(void* const* d_in, const int* in_sizes, int n_in,
                              void* d_out, int out_size, void* d_ws, size_t ws_size,
                              hipStream_t stream) {
  const float* x     = (const float*)d_in[0];  // [2,2048,2048] fp32
  const float* Wq    = (const float*)d_in[1];  // [2048,2048]
  const float* Wkv   = (const float*)d_in[2];  // [1024,2048]
  const float* Wproj = (const float*)d_in[3];  // [2048,2048]
  float* out = (float*)d_out;                  // [2,2048,2048] fp32

  const size_t NX  = (size_t)4096 * 2048;
  const size_t NWQ = (size_t)2048 * 2048;
  const size_t NWK = (size_t)1024 * 2048;
  const size_t NKV = (size_t)4096 * 1024;
  // ws (bf16): xb | Wqb | Wkvb | Wpb | kv | y  = 63 MB
  const size_t needed_ws = (NX + NWQ + NWK + NWQ + NKV + NX) * sizeof(us);

  int b0 = (n_in >= 1 && (size_t)in_sizes[0] == NX);
  int b1 = (n_in >= 2 && (size_t)in_sizes[1] == NWQ);
  int b2 = (n_in >= 3 && (size_t)in_sizes[2] == NWK);
  int b3 = (n_in >= 4 && (size_t)in_sizes[3] == NWQ);
  int ws_ok = (ws_size >= needed_ws);
  int out_ok = ((size_t)out_size == NX);
  if (!(n_in == 4 && b0 && b1 && b2 && b3 && ws_ok && out_ok)) {
    float code = 1.0e6f * (float)(n_in < 10 ? n_in : 9)
               + 1.0e5f * b0 + 1.0e4f * b1 + 1.0e3f * b2 + 1.0e2f * b3
               + 10.0f * ws_ok + 40.0f * out_ok;
    fill_diag<<<dim3((out_size + 255) / 256), dim3(256), 0, stream>>>(out, code, out_size);
    return;
  }

  us* xb    = (us*)d_ws;
  us* Wqb   = xb    + NX;
  us* Wkvb  = Wqb   + NWQ;
  us* Wpb   = Wkvb  + NWK;
  us* kvbuf = Wpb   + NWQ;
  us* ybuf  = kvbuf + NKV;
  us* qbuf  = (us*)d_out;   // q parks in d_out (bf16, 16.8 of 33.6 MB); dead
                            // before the final GEMM overwrites out with fp32.

  dim3 blk(256);
  cast_f32_bf16<<<dim3((int)(NX  / 8 / 256)), blk, 0, stream>>>(x,     xb,   (int)(NX  / 8));
  cast_f32_bf16<<<dim3((int)(NWQ / 8 / 256)), blk, 0, stream>>>(Wq,    Wqb,  (int)(NWQ / 8));
  cast_f32_bf16<<<dim3((int)(NWK / 8 / 256)), blk, 0, stream>>>(Wkv,   Wkvb, (int)(NWK / 8));
  cast_f32_bf16<<<dim3((int)(NWQ / 8 / 256)), blk, 0, stream>>>(Wproj, Wpb,  (int)(NWQ / 8));

  gemm_bt<us><<<dim3(32, 16), blk, 0, stream>>>(xb, Wqb,  qbuf,  4096, 2048, 2048);
  gemm_bt<us><<<dim3(32, 8),  blk, 0, stream>>>(xb, Wkvb, kvbuf, 4096, 1024, 2048);
  rope_kernel<<<dim3(4096), blk, 0, stream>>>(qbuf, kvbuf);
  attn_kernel<<<dim3(32, 32), blk, 0, stream>>>(qbuf, kvbuf, ybuf);
  gemm_bt<float><<<dim3(32, 16), blk, 0, stream>>>(ybuf, Wpb, out, 4096, 2048, 2048);
}

// Round 7
// 421.803 us; speedup vs baseline: 32.2751x; 1.1114x over previous
//
#include <hip/hip_runtime.h>
#include <stdint.h>

#define T_SEQ 2048
#define D_MODEL 2048
#define N_KV 4
#define HD 128
#define QKV_W 3072   // fused row width: 2048 q | 512 k | 512 v

typedef unsigned short us;
typedef __attribute__((ext_vector_type(8))) short bf16x8;
typedef __attribute__((ext_vector_type(4))) float f32x4;
typedef __attribute__((ext_vector_type(8))) unsigned short u16x8;

__device__ __forceinline__ us f2bf(float f) {
  union { float f; unsigned int u; } v; v.f = f;
  unsigned int r = v.u + 0x7FFFu + ((v.u >> 16) & 1u);
  return (us)(r >> 16);
}
__device__ __forceinline__ float bf2f(us h) {
  union { unsigned int u; float f; } v; v.u = ((unsigned int)h) << 16;
  return v.f;
}

__device__ __forceinline__ void load_lds16(const void* g, void* l) {
  __builtin_amdgcn_global_load_lds(
      (const __attribute__((address_space(1))) void*)g,
      (__attribute__((address_space(3))) void*)l, 16, 0, 0);
}

__global__ void fill_diag(float* __restrict__ out, float val, int n) {
  int i = blockIdx.x * blockDim.x + threadIdx.x;
  if (i < n) out[i] = val;
}

// ---------------------------------------------------------------------------
__global__ void cast_f32_bf16(const float* __restrict__ src,
                              us* __restrict__ dst, int n8) {
  int i = blockIdx.x * blockDim.x + threadIdx.x;
  if (i >= n8) return;
  const float4* s = (const float4*)src + (size_t)i * 2;
  float4 a = s[0], b = s[1];
  u16x8 o;
  o[0] = f2bf(a.x); o[1] = f2bf(a.y); o[2] = f2bf(a.z); o[3] = f2bf(a.w);
  o[4] = f2bf(b.x); o[5] = f2bf(b.y); o[6] = f2bf(b.z); o[7] = f2bf(b.w);
  *((u16x8*)dst + i) = o;
}

// ---------------------------------------------------------------------------
// C[M][N] = A[M][K] * B[N][K]^T, bf16 in, bf16/fp32 out. m97 structure.
// ---------------------------------------------------------------------------
template <typename OUT>
__global__ __launch_bounds__(256) void gemm_bt(
    const us* __restrict__ A, const us* __restrict__ B,
    OUT* __restrict__ C, int M, int N, int K) {
  __shared__ us As[128 * 32];
  __shared__ us Bs[128 * 32];

  const int tid  = threadIdx.x;
  const int lane = tid & 63;
  const int wave = tid >> 6;
  const int l15  = lane & 15;
  const int quad = lane >> 4;
  const int bm = blockIdx.x * 128;
  const int bn = blockIdx.y * 128;
  const int wm = (wave & 1) * 64;
  const int wn = (wave >> 1) * 64;

  f32x4 acc[4][4];
#pragma unroll
  for (int i = 0; i < 4; i++)
#pragma unroll
    for (int j = 0; j < 4; j++) acc[i][j] = (f32x4)0.f;

  const int srow = tid >> 2;
  const int scol = (tid & 3) * 8;
  const us* Ag = A + (size_t)(bm + srow) * K + scol;
  const us* Bg = B + (size_t)(bn + srow) * K + scol;
  us* AsW = &As[tid * 8];
  us* BsW = &Bs[tid * 8];
  const size_t rowskip = (size_t)64 * K;

  for (int k0 = 0; k0 < K; k0 += 32) {
    load_lds16(Ag, AsW);
    load_lds16(Ag + rowskip, AsW + 2048);
    load_lds16(Bg, BsW);
    load_lds16(Bg + rowskip, BsW + 2048);
    Ag += 32; Bg += 32;
    __syncthreads();

    bf16x8 a[4], b[4];
#pragma unroll
    for (int mt = 0; mt < 4; mt++)
      a[mt] = *(const bf16x8*)&As[(wm + mt * 16 + l15) * 32 + quad * 8];
#pragma unroll
    for (int nt = 0; nt < 4; nt++)
      b[nt] = *(const bf16x8*)&Bs[(wn + nt * 16 + l15) * 32 + quad * 8];
#pragma unroll
    for (int mt = 0; mt < 4; mt++)
#pragma unroll
      for (int nt = 0; nt < 4; nt++)
        acc[mt][nt] = __builtin_amdgcn_mfma_f32_16x16x32_bf16(a[mt], b[nt], acc[mt][nt], 0, 0, 0);
    __syncthreads();
  }

#pragma unroll
  for (int mt = 0; mt < 4; mt++) {
    int row = bm + wm + mt * 16 + quad * 4;
#pragma unroll
    for (int nt = 0; nt < 4; nt++) {
      int col = bn + wn + nt * 16 + l15;
#pragma unroll
      for (int r = 0; r < 4; r++) {
        if constexpr (sizeof(OUT) == 4)
          C[(size_t)(row + r) * N + col] = acc[mt][nt][r];
        else
          C[(size_t)(row + r) * N + col] = f2bf(acc[mt][nt][r]);
      }
    }
  }
}

// ---------------------------------------------------------------------------
// RoPE in-place on fused qkv [B*T][3072]: q heads at col h*128, k heads at
// col 2048 + hk*128. angle = t * 10000^(-i/64); pairs (i, i+64).
// ---------------------------------------------------------------------------
__global__ void rope_kernel(us* __restrict__ qkv) {
  const int row = blockIdx.x;
  const int t = row & (T_SEQ - 1);
  const int tid = threadIdx.x;
  const float L2_10K_64 = 13.287712379549449f / 64.f;
  us* rp = qkv + (size_t)row * QKV_W;

#pragma unroll
  for (int it = 0; it < 4; it++) {     // 16 q heads * 64 pairs
    int idx = it * 256 + tid;
    int h = idx >> 6, i = idx & 63;
    int base = h * HD;
    float ang = (float)t * exp2f(-(float)i * L2_10K_64);
    float s, c; sincosf(ang, &s, &c);
    float x1 = bf2f(rp[base + i]);
    float x2 = bf2f(rp[base + i + 64]);
    rp[base + i]      = f2bf(x1 * c - x2 * s);
    rp[base + i + 64] = f2bf(x2 * c + x1 * s);
  }
  {                                    // 4 k heads * 64 pairs
    int h = tid >> 6, i = tid & 63;
    int base = 2048 + h * HD;
    float ang = (float)t * exp2f(-(float)i * L2_10K_64);
    float s, c; sincosf(ang, &s, &c);
    float x1 = bf2f(rp[base + i]);
    float x2 = bf2f(rp[base + i + 64]);
    rp[base + i]      = f2bf(x1 * c - x2 * s);
    rp[base + i + 64] = f2bf(x2 * c + x1 * s);
  }
}

// ---------------------------------------------------------------------------
// Causal flash attention, GQA, balanced: block = pair of Q-tiles (31-p, p),
// each 64 rows of one (b,h); uniform 33 chunks/block. K in padded LDS rows
// (272B stride -> 2-way max on b128 reads); V transposed+XOR-swizzled;
// register-prefetch of next K/V chunk; 2 barriers/chunk.
// ---------------------------------------------------------------------------
__device__ __forceinline__ int vperm(int d) { return ((d >> 3) ^ d) & 7; }

__global__ __launch_bounds__(256) void attn_kernel(
    const us* __restrict__ qkv, us* __restrict__ y) {
  __shared__ us Ks[64][136];    // 128 data + 8 pad: 68 dwords/row = 4-bank rotation
  __shared__ us Vt[128][64];    // V^T, XOR-swizzled 8-key blocks
  __shared__ us Pl[4][16][88];  // per-wave P; 44 dwords/row = 12-bank rotation

  const int tid  = threadIdx.x;
  const int lane = tid & 63;
  const int wave = tid >> 6;
  const int l15  = lane & 15;
  const int quad = lane >> 4;
  const int p  = blockIdx.x;           // 0..15 -> tiles {31-p, p}
  const int bh = blockIdx.y;
  const int b  = bh >> 4;
  const int h  = bh & 15;
  const int hk = h >> 2;

  const us* base = qkv + (size_t)b * T_SEQ * QKV_W;
  const int kcol = 2048 + hk * HD;
  const int vcol = kcol + 512;
  const int skey = tid >> 4;           // 0..15
  const int skk  = (tid & 15) * 8;     // 0..120
  const float scale = 0.08838834764831845f;  // 1/sqrt(128)

  for (int half = 0; half < 2; half++) {
    const int x  = half ? p : 31 - p;  // long tile first
    const int m0 = x * 64;

    bf16x8 qf[4];
    {
      const us* Qrow = base + (size_t)(m0 + wave * 16 + l15) * QKV_W + h * HD;
#pragma unroll
      for (int s = 0; s < 4; s++)
        qf[s] = *(const bf16x8*)&Qrow[s * 32 + quad * 8];
    }

    f32x4 O[8];
#pragma unroll
    for (int i = 0; i < 8; i++) O[i] = (f32x4)0.f;
    float mrun[4], lrun[4];
#pragma unroll
    for (int r = 0; r < 4; r++) { mrun[r] = -INFINITY; lrun[r] = 0.f; }

    // prefetch chunk 0
    uint4 kreg[4]; u16x8 vreg[4];
#pragma unroll
    for (int r = 0; r < 4; r++) {
      const us* row = base + (size_t)(skey + r * 16) * QKV_W;
      kreg[r] = *(const uint4*)(row + kcol + skk);
      vreg[r] = *(const u16x8*)(row + vcol + skk);
    }

    for (int j = 0; j <= x; j++) {
      __syncthreads();                 // prior chunk's LDS reads done
#pragma unroll
      for (int r = 0; r < 4; r++) {
        int key = skey + r * 16;
        *(uint4*)&Ks[key][skk] = kreg[r];
#pragma unroll
        for (int i = 0; i < 8; i++) {
          int d = skk + i;
          Vt[d][key ^ (vperm(d) << 3)] = vreg[r][i];
        }
      }
      __syncthreads();                 // staging visible

      if (j < x) {                     // prefetch next chunk (latency hidden by compute)
        const int k0n = (j + 1) * 64;
#pragma unroll
        for (int r = 0; r < 4; r++) {
          const us* row = base + (size_t)(k0n + skey + r * 16) * QKV_W;
          kreg[r] = *(const uint4*)(row + kcol + skk);
          vreg[r] = *(const u16x8*)(row + vcol + skk);
        }
      }

      // S = Q K^T
      f32x4 S[4];
#pragma unroll
      for (int nt = 0; nt < 4; nt++) {
        f32x4 sa = (f32x4)0.f;
#pragma unroll
        for (int ks = 0; ks < 4; ks++) {
          bf16x8 kf = *(const bf16x8*)&Ks[nt * 16 + l15][ks * 32 + quad * 8];
          sa = __builtin_amdgcn_mfma_f32_16x16x32_bf16(qf[ks], kf, sa, 0, 0, 0);
        }
        S[nt] = sa;
      }

      const int row0 = m0 + wave * 16 + quad * 4;
      if (j == x) {                    // diagonal chunk only: mask
        const int k0 = j * 64;
#pragma unroll
        for (int nt = 0; nt < 4; nt++) {
          int col = k0 + nt * 16 + l15;
#pragma unroll
          for (int r = 0; r < 4; r++) {
            float v = S[nt][r] * scale;
            if (col > row0 + r) v = -INFINITY;
            S[nt][r] = v;
          }
        }
      } else {
#pragma unroll
        for (int nt = 0; nt < 4; nt++)
#pragma unroll
          for (int r = 0; r < 4; r++) S[nt][r] *= scale;
      }

      // online softmax
      float pr[4][4];
#pragma unroll
      for (int r = 0; r < 4; r++) {
        float mx = fmaxf(fmaxf(S[0][r], S[1][r]), fmaxf(S[2][r], S[3][r]));
#pragma unroll
        for (int off = 1; off < 16; off <<= 1)
          mx = fmaxf(mx, __shfl_xor(mx, off, 64));
        float mnew = fmaxf(mrun[r], mx);
        float alpha = __expf(mrun[r] - mnew);
        mrun[r] = mnew;
        float sum = 0.f;
#pragma unroll
        for (int nt = 0; nt < 4; nt++) {
          float pv = __expf(S[nt][r] - mnew);
          pr[nt][r] = pv;
          sum += pv;
        }
#pragma unroll
        for (int off = 1; off < 16; off <<= 1)
          sum += __shfl_xor(sum, off, 64);
        lrun[r] = lrun[r] * alpha + sum;
#pragma unroll
        for (int ot = 0; ot < 8; ot++) O[ot][r] *= alpha;
      }

      // P: C-layout -> per-wave LDS -> A-layout (no barrier: same-wave)
#pragma unroll
      for (int nt = 0; nt < 4; nt++)
#pragma unroll
        for (int r = 0; r < 4; r++)
          Pl[wave][quad * 4 + r][nt * 16 + l15] = f2bf(pr[nt][r]);

      // O += P V
#pragma unroll
      for (int ks = 0; ks < 2; ks++) {
        bf16x8 pf = *(const bf16x8*)&Pl[wave][l15][ks * 32 + quad * 8];
#pragma unroll
        for (int ot = 0; ot < 8; ot++) {
          int dcol = ot * 16 + l15;
          bf16x8 vf = *(const bf16x8*)&Vt[dcol][(ks * 32 + quad * 8) ^ (vperm(dcol) << 3)];
          O[ot] = __builtin_amdgcn_mfma_f32_16x16x32_bf16(pf, vf, O[ot], 0, 0, 0);
        }
      }
    }

    // epilogue for this tile
    const int t_out = m0 + wave * 16 + quad * 4;
#pragma unroll
    for (int r = 0; r < 4; r++) {
      float inv_l = 1.f / lrun[r];
      us* yrow = y + (size_t)(b * T_SEQ + t_out + r) * D_MODEL + h * HD;
#pragma unroll
      for (int ot = 0; ot < 8; ot++)
        yrow[ot * 16 + l15] = f2bf(O[ot][r] * inv_l);
    }
  }
}

// ---------------------------------------------------------------------------
extern "C" void kernel_launch(void* const* d_in, const int* in_sizes, int n_in,
                              void* d_out, int out_size, void* d_ws, size_t ws_size,
                              hipStream_t stream) {
  const float* x     = (const float*)d_in[0];  // [2,2048,2048] fp32
  const float* Wq    = (const float*)d_in[1];  // [2048,2048]
  const float* Wkv   = (const float*)d_in[2];  // [1024,2048]
  const float* Wproj = (const float*)d_in[3];  // [2048,2048]
  float* out = (float*)d_out;                  // [2,2048,2048] fp32

  const size_t NX  = (size_t)4096 * 2048;
  const size_t NWQ = (size_t)2048 * 2048;
  const size_t NWK = (size_t)1024 * 2048;
  // ws (bf16): xb | Wqkvb (3072x2048) | Wpb | ybuf  = 54.6 MB
  const size_t needed_ws = (NX + (NWQ + NWK) + NWQ + NX) * sizeof(us);

  int b0 = (n_in >= 1 && (size_t)in_sizes[0] == NX);
  int b1 = (n_in >= 2 && (size_t)in_sizes[1] == NWQ);
  int b2 = (n_in >= 3 && (size_t)in_sizes[2] == NWK);
  int b3 = (n_in >= 4 && (size_t)in_sizes[3] == NWQ);
  int ws_ok = (ws_size >= needed_ws);
  int out_ok = ((size_t)out_size == NX);
  if (!(n_in == 4 && b0 && b1 && b2 && b3 && ws_ok && out_ok)) {
    float code = 1.0e6f * (float)(n_in < 10 ? n_in : 9)
               + 1.0e5f * b0 + 1.0e4f * b1 + 1.0e3f * b2 + 1.0e2f * b3
               + 10.0f * ws_ok + 40.0f * out_ok;
    fill_diag<<<dim3((out_size + 255) / 256), dim3(256), 0, stream>>>(out, code, out_size);
    return;
  }

  us* xb     = (us*)d_ws;
  us* Wqkvb  = xb + NX;            // [3072][2048]: rows 0-2047 Wq, 2048-3071 Wkv
  us* Wpb    = Wqkvb + NWQ + NWK;
  us* ybuf   = Wpb + NWQ;
  us* qkvbuf = (us*)d_out;         // [4096][3072] bf16 parks in d_out (25.2 of 33.6 MB);
                                   // dead before proj GEMM overwrites out with fp32.

  dim3 blk(256);
  cast_f32_bf16<<<dim3((int)(NX  / 8 / 256)), blk, 0, stream>>>(x,     xb,          (int)(NX  / 8));
  cast_f32_bf16<<<dim3((int)(NWQ / 8 / 256)), blk, 0, stream>>>(Wq,    Wqkvb,       (int)(NWQ / 8));
  cast_f32_bf16<<<dim3((int)(NWK / 8 / 256)), blk, 0, stream>>>(Wkv,   Wqkvb + NWQ, (int)(NWK / 8));
  cast_f32_bf16<<<dim3((int)(NWQ / 8 / 256)), blk, 0, stream>>>(Wproj, Wpb,         (int)(NWQ / 8));

  gemm_bt<us><<<dim3(32, 24), blk, 0, stream>>>(xb, Wqkvb, qkvbuf, 4096, 3072, 2048);
  rope_kernel<<<dim3(4096), blk, 0, stream>>>(qkvbuf);
  attn_kernel<<<dim3(16, 32), blk, 0, stream>>>(qkvbuf, ybuf);
  gemm_bt<float><<<dim3(32, 16), blk, 0, stream>>>(ybuf, Wpb, out, 4096, 2048, 2048);
}